// Round 1
// baseline (884.885 us; speedup 1.0000x reference)
//
#include <hip/hip_runtime.h>

#define B_ROWS 32768
#define D_DIM  512

struct Ws {
    unsigned anchor_idx;   // min index with label==0
    int      cnt0;         // count of label==0
    float    acc[8];       // pos_sum[4], neg_sum[4]
    float    anorm[4];     // anchor L2 norms per modality
};

// ---------------------------------------------------------------- scan labels
__global__ void scan_labels_kernel(const int* __restrict__ label, Ws* ws) {
    int tid = blockIdx.x * blockDim.x + threadIdx.x;
    int stride = gridDim.x * blockDim.x;
    int cnt = 0;
    unsigned mymin = 0xFFFFFFFFu;
    for (int i = tid; i < B_ROWS; i += stride) {
        if (label[i] == 0) {
            cnt++;
            mymin = mymin < (unsigned)i ? mymin : (unsigned)i;
        }
    }
    // wave64 reduce
    for (int off = 32; off; off >>= 1) {
        cnt += __shfl_xor(cnt, off);
        unsigned o = (unsigned)__shfl_xor((int)mymin, off);
        mymin = mymin < o ? mymin : o;
    }
    if ((threadIdx.x & 63) == 0) {
        if (cnt) atomicAdd(&ws->cnt0, cnt);
        if (mymin != 0xFFFFFFFFu) atomicMin(&ws->anchor_idx, mymin);
    }
}

// ---------------------------------------------------------------- anchor norms
__global__ void anchor_norm_kernel(const float* __restrict__ p_t,
                                   const float* __restrict__ p_a,
                                   const float* __restrict__ s_t,
                                   const float* __restrict__ s_a,
                                   Ws* ws) {
    const float* X[4] = {p_t, p_a, s_t, s_a};
    unsigned aidx = ws->anchor_idx;
    __shared__ float red[4][4];  // [modality][wave]
    int lane = threadIdx.x & 63;
    int wid  = threadIdx.x >> 6;
    for (int m = 0; m < 4; ++m) {
        const float* a = X[m] + (size_t)aidx * D_DIM;
        float s = 0.f;
        for (int d = threadIdx.x; d < D_DIM; d += 256) {
            float v = a[d];
            s += v * v;
        }
        for (int off = 32; off; off >>= 1) s += __shfl_xor(s, off);
        if (lane == 0) red[m][wid] = s;
    }
    __syncthreads();
    if (threadIdx.x < 4) {
        int m = threadIdx.x;
        ws->anorm[m] = sqrtf(red[m][0] + red[m][1] + red[m][2] + red[m][3]);
    }
}

// ---------------------------------------------------------------- main pass
// One wave per row (grid-stride). Anchor rows cached in LDS (8 KB).
// Each lane loads 8 consecutive floats (2x float4) per modality => the wave
// reads a contiguous 2 KB segment: perfectly coalesced.
__launch_bounds__(256)
__global__ void cos_accum_kernel(const int* __restrict__ label,
                                 const float* __restrict__ p_t,
                                 const float* __restrict__ p_a,
                                 const float* __restrict__ s_t,
                                 const float* __restrict__ s_a,
                                 Ws* ws) {
    const float* X[4] = {p_t, p_a, s_t, s_a};
    __shared__ float4 anc[4][D_DIM / 4];  // 4 * 512 floats = 8 KB

    unsigned aidx = ws->anchor_idx;
    float an[4];
    an[0] = ws->anorm[0]; an[1] = ws->anorm[1];
    an[2] = ws->anorm[2]; an[3] = ws->anorm[3];

    // stage anchor rows into LDS
    for (int idx = threadIdx.x; idx < 4 * (D_DIM / 4); idx += blockDim.x) {
        int m = idx >> 7;          // /128
        int j = idx & 127;
        anc[m][j] = ((const float4*)(X[m] + (size_t)aidx * D_DIM))[j];
    }
    __syncthreads();

    int lane   = threadIdx.x & 63;
    int gwave  = (blockIdx.x * blockDim.x + threadIdx.x) >> 6;
    int nwaves = (gridDim.x * blockDim.x) >> 6;

    float pos[4] = {0.f, 0.f, 0.f, 0.f};
    float neg[4] = {0.f, 0.f, 0.f, 0.f};

    for (int row = gwave; row < B_ROWS; row += nwaves) {
        if ((unsigned)row == aidx) continue;
        bool is_pos = (label[row] == 0);
        #pragma unroll
        for (int m = 0; m < 4; ++m) {
            const float4* Xr = (const float4*)(X[m] + (size_t)row * D_DIM);
            float4 x0 = Xr[lane * 2];
            float4 x1 = Xr[lane * 2 + 1];
            float4 b0 = anc[m][lane * 2];
            float4 b1 = anc[m][lane * 2 + 1];
            float dot = x0.x * b0.x + x0.y * b0.y + x0.z * b0.z + x0.w * b0.w
                      + x1.x * b1.x + x1.y * b1.y + x1.z * b1.z + x1.w * b1.w;
            float nrm = x0.x * x0.x + x0.y * x0.y + x0.z * x0.z + x0.w * x0.w
                      + x1.x * x1.x + x1.y * x1.y + x1.z * x1.z + x1.w * x1.w;
            #pragma unroll
            for (int off = 32; off; off >>= 1) {
                dot += __shfl_xor(dot, off);
                nrm += __shfl_xor(nrm, off);
            }
            if (lane == 0) {
                float c = dot / (sqrtf(nrm) * an[m]);
                if (is_pos) pos[m] += c; else neg[m] += c;
            }
        }
    }

    if (lane == 0) {
        #pragma unroll
        for (int m = 0; m < 4; ++m) {
            atomicAdd(&ws->acc[m],     pos[m]);
            atomicAdd(&ws->acc[4 + m], neg[m]);
        }
    }
}

// ---------------------------------------------------------------- finalize
__global__ void finalize_kernel(const Ws* __restrict__ ws, float* __restrict__ out) {
    int cnt0 = ws->cnt0;
    float pos_cnt = (float)(cnt0 - 1);
    float neg_cnt = (float)(B_ROWS - cnt0);
    float total = 0.f;
    for (int m = 0; m < 4; ++m) {
        float ps = (pos_cnt > 0.f) ? ws->acc[m]     / fmaxf(pos_cnt, 1.f) : 0.f;
        float ns = (neg_cnt > 0.f) ? ws->acc[4 + m] / fmaxf(neg_cnt, 1.f) : 0.f;
        total += 2.0f - ps + ns;
    }
    out[0] = total * 0.25f;
}

extern "C" void kernel_launch(void* const* d_in, const int* in_sizes, int n_in,
                              void* d_out, int out_size, void* d_ws, size_t ws_size,
                              hipStream_t stream) {
    const int*   label = (const int*)  d_in[0];
    const float* p_t   = (const float*)d_in[1];
    const float* p_a   = (const float*)d_in[2];
    const float* s_t   = (const float*)d_in[3];
    const float* s_a   = (const float*)d_in[4];
    Ws* ws = (Ws*)d_ws;

    // anchor_idx <- 0xFFFFFFFF ; everything else <- 0
    hipMemsetAsync(d_ws, 0xFF, sizeof(unsigned), stream);
    hipMemsetAsync((char*)d_ws + sizeof(unsigned), 0,
                   sizeof(Ws) - sizeof(unsigned), stream);

    scan_labels_kernel <<<64,   256, 0, stream>>>(label, ws);
    anchor_norm_kernel <<<1,    256, 0, stream>>>(p_t, p_a, s_t, s_a, ws);
    cos_accum_kernel   <<<2048, 256, 0, stream>>>(label, p_t, p_a, s_t, s_a, ws);
    finalize_kernel    <<<1,    1,   0, stream>>>(ws, (float*)d_out);
}

// Round 2
// 94.387 us; speedup vs baseline: 9.3750x; 9.3750x over previous
//
#include <hip/hip_runtime.h>

#define B_ROWS   32768
#define D_DIM    512
#define NBLOCKS  2048     // main-pass grid
#define TPB      256      // 4 waves per block
#define NWAVES   (NBLOCKS * (TPB / 64))

struct Ws {
    unsigned anchor_idx;   // min index with label==0
    int      cnt0;         // count of label==0
    float    anorm[4];     // anchor L2 norms per modality
};
// partials live at (float*)d_ws + 64  :  [NBLOCKS][8]  (pos[4], neg[4])

// ---------------------------------------------------------------- scan labels
__global__ void scan_labels_kernel(const int* __restrict__ label, Ws* ws) {
    int tid = blockIdx.x * blockDim.x + threadIdx.x;
    int stride = gridDim.x * blockDim.x;
    int cnt = 0;
    unsigned mymin = 0xFFFFFFFFu;
    for (int i = tid; i < B_ROWS; i += stride) {
        if (label[i] == 0) {
            cnt++;
            mymin = mymin < (unsigned)i ? mymin : (unsigned)i;
        }
    }
    for (int off = 32; off; off >>= 1) {
        cnt += __shfl_xor(cnt, off);
        unsigned o = (unsigned)__shfl_xor((int)mymin, off);
        mymin = mymin < o ? mymin : o;
    }
    if ((threadIdx.x & 63) == 0) {
        if (cnt) atomicAdd(&ws->cnt0, cnt);
        if (mymin != 0xFFFFFFFFu) atomicMin(&ws->anchor_idx, mymin);
    }
}

// ---------------------------------------------------------------- anchor norms
__global__ void anchor_norm_kernel(const float* __restrict__ p_t,
                                   const float* __restrict__ p_a,
                                   const float* __restrict__ s_t,
                                   const float* __restrict__ s_a,
                                   Ws* ws) {
    const float* X[4] = {p_t, p_a, s_t, s_a};
    unsigned aidx = ws->anchor_idx;
    __shared__ float red[4][4];  // [modality][wave]
    int lane = threadIdx.x & 63;
    int wid  = threadIdx.x >> 6;
    for (int m = 0; m < 4; ++m) {
        const float* a = X[m] + (size_t)aidx * D_DIM;
        float s = 0.f;
        for (int d = threadIdx.x; d < D_DIM; d += 256) {
            float v = a[d];
            s += v * v;
        }
        for (int off = 32; off; off >>= 1) s += __shfl_xor(s, off);
        if (lane == 0) red[m][wid] = s;
    }
    __syncthreads();
    if (threadIdx.x < 4) {
        int m = threadIdx.x;
        ws->anorm[m] = sqrtf(red[m][0] + red[m][1] + red[m][2] + red[m][3]);
    }
}

// ---------------------------------------------------------------- main pass
// One wave per row (grid-stride). Anchor rows in LDS. NO global atomics:
// block-level LDS reduce, one 32B private store per block.
__launch_bounds__(TPB)
__global__ void cos_accum_kernel(const int* __restrict__ label,
                                 const float* __restrict__ p_t,
                                 const float* __restrict__ p_a,
                                 const float* __restrict__ s_t,
                                 const float* __restrict__ s_a,
                                 const Ws* __restrict__ ws,
                                 float* __restrict__ partials) {
    const float* X[4] = {p_t, p_a, s_t, s_a};
    __shared__ float4 anc[4][D_DIM / 4];  // 8 KB
    __shared__ float  red[4][8];          // [wave][pos0..3,neg0..3]

    unsigned aidx = ws->anchor_idx;
    float inv_an[4];
    #pragma unroll
    for (int m = 0; m < 4; ++m) inv_an[m] = 1.0f / ws->anorm[m];

    // stage anchor rows into LDS
    for (int idx = threadIdx.x; idx < 4 * (D_DIM / 4); idx += TPB) {
        int m = idx >> 7;
        int j = idx & 127;
        anc[m][j] = ((const float4*)(X[m] + (size_t)aidx * D_DIM))[j];
    }
    __syncthreads();

    int lane  = threadIdx.x & 63;
    int wid   = threadIdx.x >> 6;
    int gwave = blockIdx.x * (TPB / 64) + wid;

    float pos[4] = {0.f, 0.f, 0.f, 0.f};
    float neg[4] = {0.f, 0.f, 0.f, 0.f};

    for (int row = gwave; row < B_ROWS; row += NWAVES) {
        int  lab  = label[row];
        bool skip = ((unsigned)row == aidx);

        // issue ALL loads first (8x dwordx4 in flight per lane)
        float4 x[8];
        #pragma unroll
        for (int m = 0; m < 4; ++m) {
            const float4* Xr = (const float4*)(X[m] + (size_t)row * D_DIM) + lane * 2;
            x[2 * m]     = Xr[0];
            x[2 * m + 1] = Xr[1];
        }

        float dot[4], nrm[4];
        #pragma unroll
        for (int m = 0; m < 4; ++m) {
            float4 b0 = anc[m][lane * 2];
            float4 b1 = anc[m][lane * 2 + 1];
            float4 x0 = x[2 * m], x1 = x[2 * m + 1];
            dot[m] = x0.x * b0.x + x0.y * b0.y + x0.z * b0.z + x0.w * b0.w
                   + x1.x * b1.x + x1.y * b1.y + x1.z * b1.z + x1.w * b1.w;
            nrm[m] = x0.x * x0.x + x0.y * x0.y + x0.z * x0.z + x0.w * x0.w
                   + x1.x * x1.x + x1.y * x1.y + x1.z * x1.z + x1.w * x1.w;
        }
        // interleaved butterflies: 4 independent chains overlap
        #pragma unroll
        for (int off = 32; off; off >>= 1) {
            #pragma unroll
            for (int m = 0; m < 4; ++m) {
                dot[m] += __shfl_xor(dot[m], off);
                nrm[m] += __shfl_xor(nrm[m], off);
            }
        }
        if (!skip) {
            #pragma unroll
            for (int m = 0; m < 4; ++m) {
                float c = dot[m] * rsqrtf(nrm[m]) * inv_an[m];
                if (lab == 0) pos[m] += c; else neg[m] += c;
            }
        }
    }

    if (lane == 0) {
        #pragma unroll
        for (int m = 0; m < 4; ++m) {
            red[wid][m]     = pos[m];
            red[wid][4 + m] = neg[m];
        }
    }
    __syncthreads();
    if (threadIdx.x < 8) {
        int j = threadIdx.x;
        float s = red[0][j] + red[1][j] + red[2][j] + red[3][j];
        partials[blockIdx.x * 8 + j] = s;   // private slot: no contention
    }
}

// ---------------------------------------------------------------- finalize
__global__ void finalize_kernel(const Ws* __restrict__ ws,
                                const float* __restrict__ partials,
                                float* __restrict__ out) {
    __shared__ float red[256];
    int t = threadIdx.x;          // 256 threads
    int j = t & 7;
    float s = 0.f;
    for (int r = t >> 3; r < NBLOCKS; r += 32)
        s += partials[r * 8 + j];  // partials[t], coalesced
    red[t] = s;
    __syncthreads();
    if (t < 8) {
        float tot = 0.f;
        #pragma unroll
        for (int k = 0; k < 32; ++k) tot += red[k * 8 + t];
        red[t] = tot;
    }
    __syncthreads();
    if (t == 0) {
        int cnt0 = ws->cnt0;
        float pos_cnt = (float)(cnt0 - 1);
        float neg_cnt = (float)(B_ROWS - cnt0);
        float total = 0.f;
        #pragma unroll
        for (int m = 0; m < 4; ++m) {
            float ps = (pos_cnt > 0.f) ? red[m]     / fmaxf(pos_cnt, 1.f) : 0.f;
            float ns = (neg_cnt > 0.f) ? red[4 + m] / fmaxf(neg_cnt, 1.f) : 0.f;
            total += 2.0f - ps + ns;
        }
        out[0] = total * 0.25f;
    }
}

extern "C" void kernel_launch(void* const* d_in, const int* in_sizes, int n_in,
                              void* d_out, int out_size, void* d_ws, size_t ws_size,
                              hipStream_t stream) {
    const int*   label = (const int*)  d_in[0];
    const float* p_t   = (const float*)d_in[1];
    const float* p_a   = (const float*)d_in[2];
    const float* s_t   = (const float*)d_in[3];
    const float* s_a   = (const float*)d_in[4];
    Ws* ws = (Ws*)d_ws;
    float* partials = (float*)d_ws + 64;   // 256B-aligned scratch past header

    // anchor_idx <- 0xFFFFFFFF ; cnt0 <- 0 (anorm/partials are fully written)
    hipMemsetAsync(d_ws, 0xFF, sizeof(unsigned), stream);
    hipMemsetAsync((char*)d_ws + sizeof(unsigned), 0, sizeof(int), stream);

    scan_labels_kernel <<<64,      256, 0, stream>>>(label, ws);
    anchor_norm_kernel <<<1,       256, 0, stream>>>(p_t, p_a, s_t, s_a, ws);
    cos_accum_kernel   <<<NBLOCKS, TPB, 0, stream>>>(label, p_t, p_a, s_t, s_a, ws, partials);
    finalize_kernel    <<<1,       256, 0, stream>>>(ws, partials, (float*)d_out);
}

// Round 3
// 67.877 us; speedup vs baseline: 13.0367x; 1.3906x over previous
//
#include <hip/hip_runtime.h>

#define B_ROWS   32768
#define D_DIM    512
#define NBLOCKS  1024            // main-pass grid
#define TPB      256             // 4 waves per block
#define NWAVES   (NBLOCKS * (TPB / 64))   // 4096
#define RPW      (B_ROWS / NWAVES)        // 8 rows per wave, exact

struct Ws {
    unsigned anchor_idx;   // min index with label==0
    int      cnt0;         // count of label==0
};
// partials live at (float*)d_ws + 64 : [NBLOCKS][8] (pos[4], neg[4])

__device__ __forceinline__ float dot4(float4 a, float4 b) {
    return a.x * b.x + a.y * b.y + a.z * b.z + a.w * b.w;
}

// Reduce 8 independent per-lane values over all 64 lanes with 10 shuffles.
// On return, every lane in group g=(lane>>3) holds the full 64-lane total of
// value j=g  (j: 0..3 = dot[m], 4..7 = nrm[m]).
__device__ __forceinline__ float fold_reduce8(const float v[8], int lane) {
    float w[4];
    #pragma unroll
    for (int i = 0; i < 4; ++i) {
        float send = (lane & 32) ? v[i] : v[i + 4];
        float rcv  = __shfl_xor(send, 32);
        w[i] = ((lane & 32) ? v[i + 4] : v[i]) + rcv;
    }
    float u[2];
    #pragma unroll
    for (int i = 0; i < 2; ++i) {
        float send = (lane & 16) ? w[i] : w[i + 2];
        float rcv  = __shfl_xor(send, 16);
        u[i] = ((lane & 16) ? w[i + 2] : w[i]) + rcv;
    }
    float t;
    {
        float send = (lane & 8) ? u[0] : u[1];
        float rcv  = __shfl_xor(send, 8);
        t = ((lane & 8) ? u[1] : u[0]) + rcv;
    }
    t += __shfl_xor(t, 4);
    t += __shfl_xor(t, 2);
    t += __shfl_xor(t, 1);
    return t;
}

__device__ __forceinline__ void loadrow(float4 x[8], const float* const X[4],
                                        unsigned r, int lane) {
    #pragma unroll
    for (int m = 0; m < 4; ++m) {
        const float4* Xr = (const float4*)(X[m] + (size_t)r * D_DIM) + lane * 2;
        x[2 * m]     = Xr[0];
        x[2 * m + 1] = Xr[1];
    }
}

__device__ __forceinline__ void process_row(const float4 x[8], const float4 an[8],
                                            int lane, int lab, unsigned r,
                                            unsigned aidx, float inv_mine,
                                            float& posAcc, float& negAcc) {
    float v[8];
    #pragma unroll
    for (int m = 0; m < 4; ++m) {
        v[m]     = dot4(x[2 * m], an[2 * m]) + dot4(x[2 * m + 1], an[2 * m + 1]);
        v[m + 4] = dot4(x[2 * m], x[2 * m]) + dot4(x[2 * m + 1], x[2 * m + 1]);
    }
    float t     = fold_reduce8(v, lane);
    float other = __shfl_xor(t, 32);     // lane 8m (<32): t=dot_m, other=nrm_m
    if (((lane & 39) == 0) && (r != aidx)) {   // lanes 0,8,16,24
        float c = t * rsqrtf(other) * inv_mine;
        if (lab == 0) posAcc += c; else negAcc += c;
    }
}

// ---------------------------------------------------------------- scan labels
__global__ void scan_labels_kernel(const int* __restrict__ label, Ws* ws) {
    int tid = blockIdx.x * blockDim.x + threadIdx.x;
    int stride = gridDim.x * blockDim.x;
    int cnt = 0;
    unsigned mymin = 0xFFFFFFFFu;
    for (int i = tid; i < B_ROWS; i += stride) {
        if (label[i] == 0) {
            cnt++;
            mymin = mymin < (unsigned)i ? mymin : (unsigned)i;
        }
    }
    for (int off = 32; off; off >>= 1) {
        cnt += __shfl_xor(cnt, off);
        unsigned o = (unsigned)__shfl_xor((int)mymin, off);
        mymin = mymin < o ? mymin : o;
    }
    if ((threadIdx.x & 63) == 0) {
        if (cnt) atomicAdd(&ws->cnt0, cnt);
        if (mymin != 0xFFFFFFFFu) atomicMin(&ws->anchor_idx, mymin);
    }
}

// ---------------------------------------------------------------- main pass
__launch_bounds__(TPB, 2)
__global__ void cos_accum_kernel(const int* __restrict__ label,
                                 const float* __restrict__ p_t,
                                 const float* __restrict__ p_a,
                                 const float* __restrict__ s_t,
                                 const float* __restrict__ s_a,
                                 const Ws* __restrict__ ws,
                                 float* __restrict__ partials) {
    const float* X[4] = {p_t, p_a, s_t, s_a};
    __shared__ float red[TPB / 64][8];

    const unsigned aidx = ws->anchor_idx;
    const int lane = threadIdx.x & 63;
    const int wid  = threadIdx.x >> 6;
    const int gwave = blockIdx.x * (TPB / 64) + wid;

    // anchor fragments in registers (L2-broadcast global loads, once per wave)
    float4 an[8];
    #pragma unroll
    for (int m = 0; m < 4; ++m) {
        const float4* A = (const float4*)(X[m] + (size_t)aidx * D_DIM) + lane * 2;
        an[2 * m]     = A[0];
        an[2 * m + 1] = A[1];
    }

    // anchor norms: one folded reduce per wave; lanes 0,8,16,24 get 1/||a_m||
    float va[8];
    #pragma unroll
    for (int m = 0; m < 4; ++m) {
        va[m]     = dot4(an[2 * m], an[2 * m]) + dot4(an[2 * m + 1], an[2 * m + 1]);
        va[m + 4] = 0.f;
    }
    float inv_mine = rsqrtf(fold_reduce8(va, lane));

    float posAcc = 0.f, negAcc = 0.f;

    // ping-pong: next row's loads always in flight under current row's reduce
    unsigned rA = (unsigned)gwave;
    int labA = label[rA];
    float4 xa[8];
    loadrow(xa, X, rA, lane);

    #pragma unroll
    for (int k = 0; k < RPW; k += 2) {
        unsigned rB = rA + NWAVES;
        int labB = label[rB];
        float4 xb[8];
        loadrow(xb, X, rB, lane);

        process_row(xa, an, lane, labA, rA, aidx, inv_mine, posAcc, negAcc);

        unsigned rA2 = rA + 2 * NWAVES;
        if (k + 2 < RPW) {              // compile-time folded
            labA = label[rA2];
            loadrow(xa, X, rA2, lane);
        }

        process_row(xb, an, lane, labB, rB, aidx, inv_mine, posAcc, negAcc);
        rA = rA2;
    }

    if ((lane & 39) == 0) {
        int m = lane >> 3;
        red[wid][m]     = posAcc;
        red[wid][4 + m] = negAcc;
    }
    __syncthreads();
    if (threadIdx.x < 8) {
        int j = threadIdx.x;
        partials[blockIdx.x * 8 + j] = red[0][j] + red[1][j] + red[2][j] + red[3][j];
    }
}

// ---------------------------------------------------------------- finalize
__global__ void finalize_kernel(const Ws* __restrict__ ws,
                                const float* __restrict__ partials,
                                float* __restrict__ out) {
    __shared__ float red[256];
    int t = threadIdx.x;          // 256 threads
    int j = t & 7;
    float s = 0.f;
    for (int r = t >> 3; r < NBLOCKS; r += 32)
        s += partials[r * 8 + j];
    red[t] = s;
    __syncthreads();
    if (t < 8) {
        float tot = 0.f;
        #pragma unroll
        for (int k = 0; k < 32; ++k) tot += red[k * 8 + t];
        red[t] = tot;
    }
    __syncthreads();
    if (t == 0) {
        int cnt0 = ws->cnt0;
        float pos_cnt = (float)(cnt0 - 1);
        float neg_cnt = (float)(B_ROWS - cnt0);
        float total = 0.f;
        #pragma unroll
        for (int m = 0; m < 4; ++m) {
            float ps = (pos_cnt > 0.f) ? red[m]     / fmaxf(pos_cnt, 1.f) : 0.f;
            float ns = (neg_cnt > 0.f) ? red[4 + m] / fmaxf(neg_cnt, 1.f) : 0.f;
            total += 2.0f - ps + ns;
        }
        out[0] = total * 0.25f;
    }
}

extern "C" void kernel_launch(void* const* d_in, const int* in_sizes, int n_in,
                              void* d_out, int out_size, void* d_ws, size_t ws_size,
                              hipStream_t stream) {
    const int*   label = (const int*)  d_in[0];
    const float* p_t   = (const float*)d_in[1];
    const float* p_a   = (const float*)d_in[2];
    const float* s_t   = (const float*)d_in[3];
    const float* s_a   = (const float*)d_in[4];
    Ws* ws = (Ws*)d_ws;
    float* partials = (float*)d_ws + 64;   // 256B past header

    // anchor_idx <- 0xFFFFFFFF ; cnt0 <- 0
    hipMemsetAsync(d_ws, 0xFF, sizeof(unsigned), stream);
    hipMemsetAsync((char*)d_ws + sizeof(unsigned), 0, sizeof(int), stream);

    scan_labels_kernel <<<64,      256, 0, stream>>>(label, ws);
    cos_accum_kernel   <<<NBLOCKS, TPB, 0, stream>>>(label, p_t, p_a, s_t, s_a, ws, partials);
    finalize_kernel    <<<1,       256, 0, stream>>>(ws, partials, (float*)d_out);
}